// Round 12
// baseline (215.657 us; speedup 1.0000x reference)
//
#include <hip/hip_runtime.h>
#include <hip/hip_fp16.h>
#include <math.h>

// B=65536 rows, DIM=256, OUT=10.
// z = x@w_in + b_in; 4x { z = (z + tanh(z) + b_i) @ inv(W_i) }; out = softmax(z@w_out + b_out).
// Newton on a linear system converges in one step => z = c @ W^{-1}.
// Round 12 (= round 11 with the cvt_pkrtz return-type fix): MT=3 (48-row tiles,
// 24 KB LDS -> 6 blocks/CU) to cut the neither-pipe stall; v_cvt_pkrtz 1-op z pack.
// Phase 1 = degree-5 polynomial inverse (1 kernel).

typedef __attribute__((ext_vector_type(8))) short short8;
typedef __attribute__((ext_vector_type(4))) float f32x4;

// ---- helpers ----
__device__ __forceinline__ float tanh_fast(float x) {
#if __has_builtin(__builtin_amdgcn_exp2f)
  float e = __builtin_amdgcn_exp2f(x * 2.8853900817779268f);
#else
  float e = __expf(2.0f * x);
#endif
  return 1.0f - 2.0f * __builtin_amdgcn_rcpf(e + 1.0f);
}
// RNE pair pack (cold path: weights)
__device__ __forceinline__ unsigned rn_pair16(float v0, float v1) {
  __half2 h = __floats2half2_rn(v0, v1);
  return *reinterpret_cast<unsigned*>(&h);
}
// RTZ pair pack, single v_cvt_pkrtz (hot path: z)
__device__ __forceinline__ unsigned rtz_pair16(float v0, float v1) {
#if __has_builtin(__builtin_amdgcn_cvt_pkrtz)
  typedef __fp16 h2v __attribute__((ext_vector_type(2)));
  h2v h = __builtin_amdgcn_cvt_pkrtz(v0, v1);
  return *reinterpret_cast<unsigned*>(&h);
#else
  return rn_pair16(v0, v1);
#endif
}

// ---------------- Phase 1: one kernel, 256 blocks ----------------
// Blocks 0..127: matrix m = bid>>5, slab r0 = (bid&31)*8: P = 6I-15W+20W^2-15W^3+6W^4-W^5
// via 4 Horner steps on an 8-row LDS slab; pack fp16-RNE into pk layer m+1.
// Blocks 128..255: pack w_in + w_out (at 5*32768, cols>=10 zero).
// pk layout (dwords): layer*32768 + kc*4096 + nt*256 + lane*4 + d.
__global__ __launch_bounds__(256) void ns_poly_k(
    const float* __restrict__ w1, const float* __restrict__ w2,
    const float* __restrict__ w3, const float* __restrict__ w4,
    const float* __restrict__ w_in, const float* __restrict__ w_out,
    unsigned* __restrict__ pk) {
  const int bid = blockIdx.x;
  const int t = threadIdx.x;
  if (bid >= 128) {
    int idx = (bid - 128) * 256 + t;  // 0..32767
    {
      int kc = idx >> 12;
      int nt = (idx >> 8) & 15;
      int lane = (idx >> 2) & 63;
      int d = idx & 3;
      int n = nt * 16 + (lane & 15);
      int kb = kc * 32 + (lane >> 4) * 8 + d * 2;
      pk[idx] = rn_pair16(w_in[kb * 256 + n], w_in[(kb + 1) * 256 + n]);
    }
    int idx2 = idx + 32768;
    if (idx2 < 34816) {
      int r2 = idx2 - 32768;  // 0..2047
      int kc = r2 >> 8;
      int lane = (r2 >> 2) & 63;
      int d = r2 & 3;
      int n = lane & 15;
      int kb = kc * 32 + (lane >> 4) * 8 + d * 2;
      float v0 = (n < 10) ? w_out[kb * 10 + n] : 0.0f;
      float v1 = (n < 10) ? w_out[(kb + 1) * 10 + n] : 0.0f;
      pk[5 * 32768 + r2] = rn_pair16(v0, v1);
    }
    return;
  }
  const int m = bid >> 5;
  const int r0 = (bid & 31) * 8;
  const float* __restrict__ W = (m == 0) ? w1 : (m == 1) ? w2 : (m == 2) ? w3 : w4;
  __shared__ float S[8][256];

#pragma unroll
  for (int i = 0; i < 8; ++i) {
    int e = i * 256 + t;
    int r = e >> 8, c = e & 255;
    S[r][c] = (((r0 + r) == c) ? 6.0f : 0.0f) - W[(r0 + r) * 256 + c];
  }
  __syncthreads();

  const float coef[4] = {-15.0f, 20.0f, -15.0f, 6.0f};
#pragma unroll
  for (int step = 0; step < 4; ++step) {
    float acc[8];
#pragma unroll
    for (int r = 0; r < 8; ++r) acc[r] = 0.0f;
    for (int k = 0; k < 256; k += 4) {
      float4 sv[8];
#pragma unroll
      for (int r = 0; r < 8; ++r) sv[r] = *(const float4*)&S[r][k];
      float wv0 = W[(k + 0) * 256 + t];
      float wv1 = W[(k + 1) * 256 + t];
      float wv2 = W[(k + 2) * 256 + t];
      float wv3 = W[(k + 3) * 256 + t];
#pragma unroll
      for (int r = 0; r < 8; ++r) {
        acc[r] = fmaf(sv[r].x, wv0, acc[r]);
        acc[r] = fmaf(sv[r].y, wv1, acc[r]);
        acc[r] = fmaf(sv[r].z, wv2, acc[r]);
        acc[r] = fmaf(sv[r].w, wv3, acc[r]);
      }
    }
    __syncthreads();
    float cdiag = coef[step];
#pragma unroll
    for (int r = 0; r < 8; ++r)
      S[r][t] = acc[r] + (((r0 + r) == t) ? cdiag : 0.0f);
    __syncthreads();
  }

  const int kc = r0 >> 5;
  const int quad = (r0 >> 3) & 3;
#pragma unroll
  for (int i = 0; i < 4; ++i) {
    int q = i * 256 + t;
    int nt = q >> 6;
    int n16 = (q >> 2) & 15;
    int d = q & 3;
    int lane = quad * 16 + n16;
    int n = nt * 16 + n16;
    unsigned word = rn_pair16(S[d * 2][n], S[d * 2 + 1][n]);
    pk[(m + 1) * 32768 + kc * 4096 + nt * 256 + lane * 4 + d] = word;
  }
}

// ---------------- Phase 2: fused pipeline ----------------
// MT*16 rows/block (MT=3 -> 48 rows, 24 KB LDS, grid 1366, 6 blocks/CU); 4 waves,
// wave w owns cols [w*64, w*64+64). z single fp16 plane, XOR swizzle:
//   idx16(r,k) = r*256 + ((k>>3) ^ (r&31))*8 + (k&7)
// Tail block (grow0=65520): loads row-clamped, stores guarded (compile-time MT,
// no dynamic indexing -- round-4 spill lesson).
template <int MT>
__global__ __launch_bounds__(256, 6) void fused_k(
    const float* __restrict__ x, const unsigned* __restrict__ pk,
    const float* __restrict__ b_in,
    const float* __restrict__ b1, const float* __restrict__ b2,
    const float* __restrict__ b3, const float* __restrict__ b4,
    const float* __restrict__ b_out, float* __restrict__ out) {
  constexpr int NR = MT * 16;
  __shared__ unsigned short zpl[NR * 256];  // 24 KB for MT=3
  const int t = threadIdx.x;
  const int ln = t & 63;
  const int wv = t >> 6;
  const int quad = ln >> 4;
  const int n16 = ln & 15;
  const int grow0 = blockIdx.x * NR;

  // ---- stage x as fp16 plane (row-clamped for tail) ----
#pragma unroll
  for (int i = 0; i < MT * 4; ++i) {
    int e = i * 1024 + t * 4;
    int r = e >> 8, c = e & 255;
    int gr = min(grow0 + r, 65535);
    float4 v = *(const float4*)(x + gr * 256 + c);
    int idx = r * 256 + (((c >> 3) ^ (r & 31)) * 8) + (c & 7);
    uint2 zp;
    zp.x = rtz_pair16(v.x, v.y);
    zp.y = rtz_pair16(v.z, v.w);
    *(uint2*)&zpl[idx] = zp;
  }
  __syncthreads();

  const float* bnv[4] = {b1, b2, b3, b4};
  f32x4 acc[MT][4];

  for (int layer = 0; layer < 5; ++layer) {
    const unsigned* pkl = pk + layer * 32768 + wv * 1024 + ln * 4;
#pragma unroll
    for (int mt = 0; mt < MT; ++mt)
#pragma unroll
      for (int nt = 0; nt < 4; ++nt) acc[mt][nt] = (f32x4){0.f, 0.f, 0.f, 0.f};

#pragma unroll 2
    for (int kc = 0; kc < 8; ++kc) {
      short8 wh[4];
      const unsigned* pb = pkl + kc * 4096;
#pragma unroll
      for (int nt = 0; nt < 4; ++nt) wh[nt] = *(const short8*)(pb + nt * 256);
#pragma unroll
      for (int mt = 0; mt < MT; ++mt) {
        int mm = mt * 16 + n16;
        int idx = mm * 256 + (((kc * 4 + quad) ^ (mm & 31)) * 8);
        short8 zf = *(const short8*)&zpl[idx];
#pragma unroll
        for (int nt = 0; nt < 4; ++nt)
          acc[mt][nt] = __builtin_amdgcn_mfma_f32_16x16x32_f16(wh[nt], zf, acc[mt][nt], 0, 0, 0);
      }
    }
    __syncthreads();  // all z reads of this layer done

    // epilogue: lane owns rows mt*16+n16, cols colb..colb+3 (one b64 write each)
#pragma unroll
    for (int nt = 0; nt < 4; ++nt) {
      int colb = wv * 64 + nt * 16 + quad * 4;
      float4 bi = make_float4(0.f, 0.f, 0.f, 0.f);
      float4 bn4 = bi;
      if (layer == 0) bi = *(const float4*)(b_in + colb);
      if (layer < 4) bn4 = *(const float4*)(bnv[layer] + colb);
#pragma unroll
      for (int mt = 0; mt < MT; ++mt) {
        int row = mt * 16 + n16;
        float v0 = acc[mt][nt][0] + bi.x;
        float v1 = acc[mt][nt][1] + bi.y;
        float v2 = acc[mt][nt][2] + bi.z;
        float v3 = acc[mt][nt][3] + bi.w;
        if (layer < 4) {
          v0 = v0 + tanh_fast(v0) + bn4.x;
          v1 = v1 + tanh_fast(v1) + bn4.y;
          v2 = v2 + tanh_fast(v2) + bn4.z;
          v3 = v3 + tanh_fast(v3) + bn4.w;
        }
        int idx = row * 256 + (((colb >> 3) ^ (row & 31)) * 8) + (colb & 7);
        uint2 zp;
        zp.x = rtz_pair16(v0, v1);
        zp.y = rtz_pair16(v2, v3);
        *(uint2*)&zpl[idx] = zp;
      }
    }
    __syncthreads();
  }

  // ---- logits: wave w reduces k-slice [w*64, w*64+64) ----
  f32x4 lacc[MT];
#pragma unroll
  for (int mt = 0; mt < MT; ++mt) lacc[mt] = (f32x4){0.f, 0.f, 0.f, 0.f};
  const unsigned* pw = pk + 5 * 32768 + ln * 4;
#pragma unroll
  for (int kk = 0; kk < 2; ++kk) {
    int kc = wv * 2 + kk;
    short8 wh = *(const short8*)(pw + kc * 256);
#pragma unroll
    for (int mt = 0; mt < MT; ++mt) {
      int mm = mt * 16 + n16;
      int idx = mm * 256 + (((kc * 4 + quad) ^ (mm & 31)) * 8);
      short8 zf = *(const short8*)&zpl[idx];
      lacc[mt] = __builtin_amdgcn_mfma_f32_16x16x32_f16(wh, zf, lacc[mt], 0, 0, 0);
    }
  }
  __syncthreads();
  float* pbuf = (float*)zpl;  // [wave][NR][16] floats = 12 KB for MT=3
#pragma unroll
  for (int mt = 0; mt < MT; ++mt) {
    int addr = wv * (NR * 16) + (mt * 16 + n16) * 16 + quad * 4;
    *(f32x4*)&pbuf[addr] = lacc[mt];
  }
  __syncthreads();
  if (t < NR && grow0 + t < 65536) {
    int r = t;
    float lg[10];
    float mx = -1e30f;
#pragma unroll
    for (int j = 0; j < 10; ++j) {
      float s = b_out[j];
#pragma unroll
      for (int w2 = 0; w2 < 4; ++w2) s += pbuf[w2 * (NR * 16) + r * 16 + j];
      lg[j] = s;
      mx = fmaxf(mx, s);
    }
    float sum = 0.f;
#pragma unroll
    for (int j = 0; j < 10; ++j) {
      lg[j] = __expf(lg[j] - mx);
      sum += lg[j];
    }
    float inv = 1.0f / sum;
    float* op = out + (grow0 + r) * 10;
#pragma unroll
    for (int j = 0; j < 10; ++j) op[j] = lg[j] * inv;
  }
}

extern "C" void kernel_launch(void* const* d_in, const int* in_sizes, int n_in,
                              void* d_out, int out_size, void* d_ws, size_t ws_size,
                              hipStream_t stream) {
  const float* x     = (const float*)d_in[0];
  const float* w_in  = (const float*)d_in[1];
  const float* b_in  = (const float*)d_in[2];
  const float* w_out = (const float*)d_in[3];
  const float* b_out = (const float*)d_in[4];
  const float* w1 = (const float*)d_in[5];
  const float* b1 = (const float*)d_in[6];
  const float* w2 = (const float*)d_in[7];
  const float* b2 = (const float*)d_in[8];
  const float* w3 = (const float*)d_in[9];
  const float* b3 = (const float*)d_in[10];
  const float* w4 = (const float*)d_in[11];
  const float* b4 = (const float*)d_in[12];
  float* out = (float*)d_out;

  unsigned* pk = (unsigned*)d_ws;  // 165888 dwords

  ns_poly_k<<<256, 256, 0, stream>>>(w1, w2, w3, w4, w_in, w_out, pk);
  // 1366 blocks x 48 rows = 65568 >= 65536 (tail clamps/guards)
  fused_k<3><<<1366, 256, 0, stream>>>(x, pk, b_in, b1, b2, b3, b4, b_out, out);
}

// Round 13
// 207.971 us; speedup vs baseline: 1.0370x; 1.0370x over previous
//
#include <hip/hip_runtime.h>
#include <hip/hip_fp16.h>
#include <math.h>

// B=65536 rows, DIM=256, OUT=10.
// z = x@w_in + b_in; 4x { z = (z + tanh(z) + b_i) @ inv(W_i) }; out = softmax(z@w_out + b_out).
// Newton on a linear system converges in one step => z = c @ W^{-1}.
// Round 13 = round 12 with __launch_bounds__(256,5) (cap ~102 VGPR): round 12's
// (256,6) cap (~85) spilled the accumulators (VGPR 40, WRITE_SIZE 25 MB, +14us).
// MT=3 (48-row tiles, 24 KB LDS -> 5 blocks/CU); v_cvt_pkrtz 1-op z pack.
// Phase 1 = degree-5 polynomial inverse (1 kernel).

typedef __attribute__((ext_vector_type(8))) short short8;
typedef __attribute__((ext_vector_type(4))) float f32x4;

// ---- helpers ----
__device__ __forceinline__ float tanh_fast(float x) {
#if __has_builtin(__builtin_amdgcn_exp2f)
  float e = __builtin_amdgcn_exp2f(x * 2.8853900817779268f);
#else
  float e = __expf(2.0f * x);
#endif
  return 1.0f - 2.0f * __builtin_amdgcn_rcpf(e + 1.0f);
}
// RNE pair pack (cold path: weights)
__device__ __forceinline__ unsigned rn_pair16(float v0, float v1) {
  __half2 h = __floats2half2_rn(v0, v1);
  return *reinterpret_cast<unsigned*>(&h);
}
// RTZ pair pack, single v_cvt_pkrtz (hot path: z)
__device__ __forceinline__ unsigned rtz_pair16(float v0, float v1) {
#if __has_builtin(__builtin_amdgcn_cvt_pkrtz)
  typedef __fp16 h2v __attribute__((ext_vector_type(2)));
  h2v h = __builtin_amdgcn_cvt_pkrtz(v0, v1);
  return *reinterpret_cast<unsigned*>(&h);
#else
  return rn_pair16(v0, v1);
#endif
}

// ---------------- Phase 1: one kernel, 256 blocks ----------------
// Blocks 0..127: matrix m = bid>>5, slab r0 = (bid&31)*8: P = 6I-15W+20W^2-15W^3+6W^4-W^5
// via 4 Horner steps on an 8-row LDS slab; pack fp16-RNE into pk layer m+1.
// Blocks 128..255: pack w_in + w_out (at 5*32768, cols>=10 zero).
// pk layout (dwords): layer*32768 + kc*4096 + nt*256 + lane*4 + d.
__global__ __launch_bounds__(256) void ns_poly_k(
    const float* __restrict__ w1, const float* __restrict__ w2,
    const float* __restrict__ w3, const float* __restrict__ w4,
    const float* __restrict__ w_in, const float* __restrict__ w_out,
    unsigned* __restrict__ pk) {
  const int bid = blockIdx.x;
  const int t = threadIdx.x;
  if (bid >= 128) {
    int idx = (bid - 128) * 256 + t;  // 0..32767
    {
      int kc = idx >> 12;
      int nt = (idx >> 8) & 15;
      int lane = (idx >> 2) & 63;
      int d = idx & 3;
      int n = nt * 16 + (lane & 15);
      int kb = kc * 32 + (lane >> 4) * 8 + d * 2;
      pk[idx] = rn_pair16(w_in[kb * 256 + n], w_in[(kb + 1) * 256 + n]);
    }
    int idx2 = idx + 32768;
    if (idx2 < 34816) {
      int r2 = idx2 - 32768;  // 0..2047
      int kc = r2 >> 8;
      int lane = (r2 >> 2) & 63;
      int d = r2 & 3;
      int n = lane & 15;
      int kb = kc * 32 + (lane >> 4) * 8 + d * 2;
      float v0 = (n < 10) ? w_out[kb * 10 + n] : 0.0f;
      float v1 = (n < 10) ? w_out[(kb + 1) * 10 + n] : 0.0f;
      pk[5 * 32768 + r2] = rn_pair16(v0, v1);
    }
    return;
  }
  const int m = bid >> 5;
  const int r0 = (bid & 31) * 8;
  const float* __restrict__ W = (m == 0) ? w1 : (m == 1) ? w2 : (m == 2) ? w3 : w4;
  __shared__ float S[8][256];

#pragma unroll
  for (int i = 0; i < 8; ++i) {
    int e = i * 256 + t;
    int r = e >> 8, c = e & 255;
    S[r][c] = (((r0 + r) == c) ? 6.0f : 0.0f) - W[(r0 + r) * 256 + c];
  }
  __syncthreads();

  const float coef[4] = {-15.0f, 20.0f, -15.0f, 6.0f};
#pragma unroll
  for (int step = 0; step < 4; ++step) {
    float acc[8];
#pragma unroll
    for (int r = 0; r < 8; ++r) acc[r] = 0.0f;
    for (int k = 0; k < 256; k += 4) {
      float4 sv[8];
#pragma unroll
      for (int r = 0; r < 8; ++r) sv[r] = *(const float4*)&S[r][k];
      float wv0 = W[(k + 0) * 256 + t];
      float wv1 = W[(k + 1) * 256 + t];
      float wv2 = W[(k + 2) * 256 + t];
      float wv3 = W[(k + 3) * 256 + t];
#pragma unroll
      for (int r = 0; r < 8; ++r) {
        acc[r] = fmaf(sv[r].x, wv0, acc[r]);
        acc[r] = fmaf(sv[r].y, wv1, acc[r]);
        acc[r] = fmaf(sv[r].z, wv2, acc[r]);
        acc[r] = fmaf(sv[r].w, wv3, acc[r]);
      }
    }
    __syncthreads();
    float cdiag = coef[step];
#pragma unroll
    for (int r = 0; r < 8; ++r)
      S[r][t] = acc[r] + (((r0 + r) == t) ? cdiag : 0.0f);
    __syncthreads();
  }

  const int kc = r0 >> 5;
  const int quad = (r0 >> 3) & 3;
#pragma unroll
  for (int i = 0; i < 4; ++i) {
    int q = i * 256 + t;
    int nt = q >> 6;
    int n16 = (q >> 2) & 15;
    int d = q & 3;
    int lane = quad * 16 + n16;
    int n = nt * 16 + n16;
    unsigned word = rn_pair16(S[d * 2][n], S[d * 2 + 1][n]);
    pk[(m + 1) * 32768 + kc * 4096 + nt * 256 + lane * 4 + d] = word;
  }
}

// ---------------- Phase 2: fused pipeline ----------------
// MT*16 rows/block (MT=3 -> 48 rows, 24 KB LDS, grid 1366, 5 blocks/CU); 4 waves,
// wave w owns cols [w*64, w*64+64). z single fp16 plane, XOR swizzle:
//   idx16(r,k) = r*256 + ((k>>3) ^ (r&31))*8 + (k&7)
// Tail block (grow0=65520): loads row-clamped, stores guarded (compile-time MT,
// no dynamic indexing -- round-4 spill lesson; launch_bounds cap >= ~102 VGPR --
// round-12 spill lesson).
template <int MT>
__global__ __launch_bounds__(256, 5) void fused_k(
    const float* __restrict__ x, const unsigned* __restrict__ pk,
    const float* __restrict__ b_in,
    const float* __restrict__ b1, const float* __restrict__ b2,
    const float* __restrict__ b3, const float* __restrict__ b4,
    const float* __restrict__ b_out, float* __restrict__ out) {
  constexpr int NR = MT * 16;
  __shared__ unsigned short zpl[NR * 256];  // 24 KB for MT=3
  const int t = threadIdx.x;
  const int ln = t & 63;
  const int wv = t >> 6;
  const int quad = ln >> 4;
  const int n16 = ln & 15;
  const int grow0 = blockIdx.x * NR;

  // ---- stage x as fp16 plane (row-clamped for tail) ----
#pragma unroll
  for (int i = 0; i < MT * 4; ++i) {
    int e = i * 1024 + t * 4;
    int r = e >> 8, c = e & 255;
    int gr = min(grow0 + r, 65535);
    float4 v = *(const float4*)(x + gr * 256 + c);
    int idx = r * 256 + (((c >> 3) ^ (r & 31)) * 8) + (c & 7);
    uint2 zp;
    zp.x = rtz_pair16(v.x, v.y);
    zp.y = rtz_pair16(v.z, v.w);
    *(uint2*)&zpl[idx] = zp;
  }
  __syncthreads();

  const float* bnv[4] = {b1, b2, b3, b4};
  f32x4 acc[MT][4];

  for (int layer = 0; layer < 5; ++layer) {
    const unsigned* pkl = pk + layer * 32768 + wv * 1024 + ln * 4;
#pragma unroll
    for (int mt = 0; mt < MT; ++mt)
#pragma unroll
      for (int nt = 0; nt < 4; ++nt) acc[mt][nt] = (f32x4){0.f, 0.f, 0.f, 0.f};

#pragma unroll 2
    for (int kc = 0; kc < 8; ++kc) {
      short8 wh[4];
      const unsigned* pb = pkl + kc * 4096;
#pragma unroll
      for (int nt = 0; nt < 4; ++nt) wh[nt] = *(const short8*)(pb + nt * 256);
#pragma unroll
      for (int mt = 0; mt < MT; ++mt) {
        int mm = mt * 16 + n16;
        int idx = mm * 256 + (((kc * 4 + quad) ^ (mm & 31)) * 8);
        short8 zf = *(const short8*)&zpl[idx];
#pragma unroll
        for (int nt = 0; nt < 4; ++nt)
          acc[mt][nt] = __builtin_amdgcn_mfma_f32_16x16x32_f16(wh[nt], zf, acc[mt][nt], 0, 0, 0);
      }
    }
    __syncthreads();  // all z reads of this layer done

    // epilogue: lane owns rows mt*16+n16, cols colb..colb+3 (one b64 write each)
#pragma unroll
    for (int nt = 0; nt < 4; ++nt) {
      int colb = wv * 64 + nt * 16 + quad * 4;
      float4 bi = make_float4(0.f, 0.f, 0.f, 0.f);
      float4 bn4 = bi;
      if (layer == 0) bi = *(const float4*)(b_in + colb);
      if (layer < 4) bn4 = *(const float4*)(bnv[layer] + colb);
#pragma unroll
      for (int mt = 0; mt < MT; ++mt) {
        int row = mt * 16 + n16;
        float v0 = acc[mt][nt][0] + bi.x;
        float v1 = acc[mt][nt][1] + bi.y;
        float v2 = acc[mt][nt][2] + bi.z;
        float v3 = acc[mt][nt][3] + bi.w;
        if (layer < 4) {
          v0 = v0 + tanh_fast(v0) + bn4.x;
          v1 = v1 + tanh_fast(v1) + bn4.y;
          v2 = v2 + tanh_fast(v2) + bn4.z;
          v3 = v3 + tanh_fast(v3) + bn4.w;
        }
        int idx = row * 256 + (((colb >> 3) ^ (row & 31)) * 8) + (colb & 7);
        uint2 zp;
        zp.x = rtz_pair16(v0, v1);
        zp.y = rtz_pair16(v2, v3);
        *(uint2*)&zpl[idx] = zp;
      }
    }
    __syncthreads();
  }

  // ---- logits: wave w reduces k-slice [w*64, w*64+64) ----
  f32x4 lacc[MT];
#pragma unroll
  for (int mt = 0; mt < MT; ++mt) lacc[mt] = (f32x4){0.f, 0.f, 0.f, 0.f};
  const unsigned* pw = pk + 5 * 32768 + ln * 4;
#pragma unroll
  for (int kk = 0; kk < 2; ++kk) {
    int kc = wv * 2 + kk;
    short8 wh = *(const short8*)(pw + kc * 256);
#pragma unroll
    for (int mt = 0; mt < MT; ++mt) {
      int mm = mt * 16 + n16;
      int idx = mm * 256 + (((kc * 4 + quad) ^ (mm & 31)) * 8);
      short8 zf = *(const short8*)&zpl[idx];
      lacc[mt] = __builtin_amdgcn_mfma_f32_16x16x32_f16(wh, zf, lacc[mt], 0, 0, 0);
    }
  }
  __syncthreads();
  float* pbuf = (float*)zpl;  // [wave][NR][16] floats = 12 KB for MT=3
#pragma unroll
  for (int mt = 0; mt < MT; ++mt) {
    int addr = wv * (NR * 16) + (mt * 16 + n16) * 16 + quad * 4;
    *(f32x4*)&pbuf[addr] = lacc[mt];
  }
  __syncthreads();
  if (t < NR && grow0 + t < 65536) {
    int r = t;
    float lg[10];
    float mx = -1e30f;
#pragma unroll
    for (int j = 0; j < 10; ++j) {
      float s = b_out[j];
#pragma unroll
      for (int w2 = 0; w2 < 4; ++w2) s += pbuf[w2 * (NR * 16) + r * 16 + j];
      lg[j] = s;
      mx = fmaxf(mx, s);
    }
    float sum = 0.f;
#pragma unroll
    for (int j = 0; j < 10; ++j) {
      lg[j] = __expf(lg[j] - mx);
      sum += lg[j];
    }
    float inv = 1.0f / sum;
    float* op = out + (grow0 + r) * 10;
#pragma unroll
    for (int j = 0; j < 10; ++j) op[j] = lg[j] * inv;
  }
}

extern "C" void kernel_launch(void* const* d_in, const int* in_sizes, int n_in,
                              void* d_out, int out_size, void* d_ws, size_t ws_size,
                              hipStream_t stream) {
  const float* x     = (const float*)d_in[0];
  const float* w_in  = (const float*)d_in[1];
  const float* b_in  = (const float*)d_in[2];
  const float* w_out = (const float*)d_in[3];
  const float* b_out = (const float*)d_in[4];
  const float* w1 = (const float*)d_in[5];
  const float* b1 = (const float*)d_in[6];
  const float* w2 = (const float*)d_in[7];
  const float* b2 = (const float*)d_in[8];
  const float* w3 = (const float*)d_in[9];
  const float* b3 = (const float*)d_in[10];
  const float* w4 = (const float*)d_in[11];
  const float* b4 = (const float*)d_in[12];
  float* out = (float*)d_out;

  unsigned* pk = (unsigned*)d_ws;  // 165888 dwords

  ns_poly_k<<<256, 256, 0, stream>>>(w1, w2, w3, w4, w_in, w_out, pk);
  // 1366 blocks x 48 rows = 65568 >= 65536 (tail clamps/guards)
  fused_k<3><<<1366, 256, 0, stream>>>(x, pk, b_in, b1, b2, b3, b4, b_out, out);
}

// Round 14
// 183.088 us; speedup vs baseline: 1.1779x; 1.1359x over previous
//
#include <hip/hip_runtime.h>
#include <hip/hip_fp16.h>
#include <math.h>

// B=65536 rows, DIM=256, OUT=10.
// z = x@w_in + b_in; 4x { z = (z + tanh(z) + b_i) @ inv(W_i) }; out = softmax(z@w_out + b_out).
// Newton on a linear system converges in one step => z = c @ W^{-1}.
// Round 14: fused_k = round-10 winner (MT=4, 4 blocks/CU — MT=3/5-blk and MT=8/2-blk
// both measured slower) + v_cvt_pkrtz z pack (validated R12/13). Phase 1 split to
// 4-row slabs (384 blocks) to cut its latency-bound serial time.

typedef __attribute__((ext_vector_type(8))) short short8;
typedef __attribute__((ext_vector_type(4))) float f32x4;

// ---- helpers ----
__device__ __forceinline__ float tanh_fast(float x) {
#if __has_builtin(__builtin_amdgcn_exp2f)
  float e = __builtin_amdgcn_exp2f(x * 2.8853900817779268f);
#else
  float e = __expf(2.0f * x);
#endif
  return 1.0f - 2.0f * __builtin_amdgcn_rcpf(e + 1.0f);
}
// RNE pair pack (cold path: weights)
__device__ __forceinline__ unsigned rn_pair16(float v0, float v1) {
  __half2 h = __floats2half2_rn(v0, v1);
  return *reinterpret_cast<unsigned*>(&h);
}
// RTZ pair pack, single v_cvt_pkrtz (hot path: z)
__device__ __forceinline__ unsigned rtz_pair16(float v0, float v1) {
#if __has_builtin(__builtin_amdgcn_cvt_pkrtz)
  typedef __fp16 h2v __attribute__((ext_vector_type(2)));
  h2v h = __builtin_amdgcn_cvt_pkrtz(v0, v1);
  return *reinterpret_cast<unsigned*>(&h);
#else
  return rn_pair16(v0, v1);
#endif
}

// ---------------- Phase 1: one kernel, 384 blocks ----------------
// Blocks 0..255: matrix m = bid>>6, 4-row slab r0 = (bid&63)*4:
//   P = 6I -15W +20W^2 -15W^3 +6W^4 -W^5 via 4 Horner steps (mult by original W);
//   pack fp16-RNE into pk layer m+1.
// Blocks 256..383: pack w_in + w_out (at 5*32768, cols>=10 zero).
// pk layout (dwords): layer*32768 + kc*4096 + nt*256 + lane*4 + d;
// word d of lane(quad,n16) = M[kb][n] lo16 | M[kb+1][n] hi16, kb=kc*32+quad*8+2d, n=nt*16+n16.
__global__ __launch_bounds__(256) void ns_poly_k(
    const float* __restrict__ w1, const float* __restrict__ w2,
    const float* __restrict__ w3, const float* __restrict__ w4,
    const float* __restrict__ w_in, const float* __restrict__ w_out,
    unsigned* __restrict__ pk) {
  const int bid = blockIdx.x;
  const int t = threadIdx.x;
  if (bid >= 256) {
    int idx = (bid - 256) * 256 + t;  // 0..32767
    {
      int kc = idx >> 12;
      int nt = (idx >> 8) & 15;
      int lane = (idx >> 2) & 63;
      int d = idx & 3;
      int n = nt * 16 + (lane & 15);
      int kb = kc * 32 + (lane >> 4) * 8 + d * 2;
      pk[idx] = rn_pair16(w_in[kb * 256 + n], w_in[(kb + 1) * 256 + n]);
    }
    int idx2 = idx + 32768;
    if (idx2 < 34816) {
      int r2 = idx2 - 32768;  // 0..2047
      int kc = r2 >> 8;
      int lane = (r2 >> 2) & 63;
      int d = r2 & 3;
      int n = lane & 15;
      int kb = kc * 32 + (lane >> 4) * 8 + d * 2;
      float v0 = (n < 10) ? w_out[kb * 10 + n] : 0.0f;
      float v1 = (n < 10) ? w_out[(kb + 1) * 10 + n] : 0.0f;
      pk[5 * 32768 + r2] = rn_pair16(v0, v1);
    }
    return;
  }
  const int m = bid >> 6;           // matrix 0..3
  const int r0 = (bid & 63) * 4;    // slab start row (4 rows)
  const float* __restrict__ W = (m == 0) ? w1 : (m == 1) ? w2 : (m == 2) ? w3 : w4;
  __shared__ float S[4][256];

  // init: P = 6I - W (slab rows r0..r0+3)
#pragma unroll
  for (int i = 0; i < 4; ++i) {
    int e = i * 256 + t;
    int r = e >> 8, c = e & 255;
    S[r][c] = (((r0 + r) == c) ? 6.0f : 0.0f) - W[(r0 + r) * 256 + c];
  }
  __syncthreads();

  const float coef[4] = {-15.0f, 20.0f, -15.0f, 6.0f};
#pragma unroll
  for (int step = 0; step < 4; ++step) {
    float acc[4];
#pragma unroll
    for (int r = 0; r < 4; ++r) acc[r] = 0.0f;
    for (int k = 0; k < 256; k += 4) {
      float4 sv[4];
#pragma unroll
      for (int r = 0; r < 4; ++r) sv[r] = *(const float4*)&S[r][k];
      float wv0 = W[(k + 0) * 256 + t];
      float wv1 = W[(k + 1) * 256 + t];
      float wv2 = W[(k + 2) * 256 + t];
      float wv3 = W[(k + 3) * 256 + t];
#pragma unroll
      for (int r = 0; r < 4; ++r) {
        acc[r] = fmaf(sv[r].x, wv0, acc[r]);
        acc[r] = fmaf(sv[r].y, wv1, acc[r]);
        acc[r] = fmaf(sv[r].z, wv2, acc[r]);
        acc[r] = fmaf(sv[r].w, wv3, acc[r]);
      }
    }
    __syncthreads();
    float cdiag = coef[step];
#pragma unroll
    for (int r = 0; r < 4; ++r)
      S[r][t] = acc[r] + (((r0 + r) == t) ? cdiag : 0.0f);
    __syncthreads();
  }

  // ---- pack slab: kc = r0>>5, quad = (r0>>3)&3, d in {d0, d0+1}, d0 = (r0&7)>>1 ----
  const int kc = r0 >> 5;
  const int quad = (r0 >> 3) & 3;
  const int d0 = (r0 & 7) >> 1;
#pragma unroll
  for (int i = 0; i < 2; ++i) {
    int q = i * 256 + t;        // 0..511 = nt*32 + n16*2 + dd
    int nt = q >> 5;            // 0..15
    int n16 = (q >> 1) & 15;
    int dd = q & 1;
    int n = nt * 16 + n16;
    int lane = quad * 16 + n16;
    unsigned word = rn_pair16(S[2 * dd][n], S[2 * dd + 1][n]);
    pk[(m + 1) * 32768 + kc * 4096 + nt * 256 + lane * 4 + (d0 + dd)] = word;
  }
}

// ---------------- Phase 2: fused pipeline (round-10 winner) ----------------
// MT*16 rows/block (MT=4 -> 64 rows, 32 KB LDS, grid 1024, 4 blocks/CU); 4 waves,
// wave w owns cols [w*64, w*64+64). z single fp16 plane, XOR swizzle:
//   idx16(r,k) = r*256 + ((k>>3) ^ (r&31))*8 + (k&7)
template <int MT>
__global__ __launch_bounds__(256, 4) void fused_k(
    const float* __restrict__ x, const unsigned* __restrict__ pk,
    const float* __restrict__ b_in,
    const float* __restrict__ b1, const float* __restrict__ b2,
    const float* __restrict__ b3, const float* __restrict__ b4,
    const float* __restrict__ b_out, float* __restrict__ out) {
  constexpr int NR = MT * 16;
  __shared__ unsigned short zpl[NR * 256];  // 32 KB for MT=4
  const int t = threadIdx.x;
  const int ln = t & 63;
  const int wv = t >> 6;
  const int quad = ln >> 4;
  const int n16 = ln & 15;
  const int grow0 = blockIdx.x * NR;

  // ---- stage x as fp16 plane ----
#pragma unroll
  for (int i = 0; i < MT * 4; ++i) {
    int e = i * 1024 + t * 4;
    int r = e >> 8, c = e & 255;
    float4 v = *(const float4*)(x + (grow0 + r) * 256 + c);
    int idx = r * 256 + (((c >> 3) ^ (r & 31)) * 8) + (c & 7);
    uint2 zp;
    zp.x = rtz_pair16(v.x, v.y);
    zp.y = rtz_pair16(v.z, v.w);
    *(uint2*)&zpl[idx] = zp;
  }
  __syncthreads();

  const float* bnv[4] = {b1, b2, b3, b4};
  f32x4 acc[MT][4];

  for (int layer = 0; layer < 5; ++layer) {
    const unsigned* pkl = pk + layer * 32768 + wv * 1024 + ln * 4;
#pragma unroll
    for (int mt = 0; mt < MT; ++mt)
#pragma unroll
      for (int nt = 0; nt < 4; ++nt) acc[mt][nt] = (f32x4){0.f, 0.f, 0.f, 0.f};

#pragma unroll 2
    for (int kc = 0; kc < 8; ++kc) {
      short8 wh[4], zf[MT];
      const unsigned* pb = pkl + kc * 4096;
#pragma unroll
      for (int nt = 0; nt < 4; ++nt) wh[nt] = *(const short8*)(pb + nt * 256);
#pragma unroll
      for (int mt = 0; mt < MT; ++mt) {
        int mm = mt * 16 + n16;
        int idx = mm * 256 + (((kc * 4 + quad) ^ (mm & 31)) * 8);
        zf[mt] = *(const short8*)&zpl[idx];
      }
#pragma unroll
      for (int mt = 0; mt < MT; ++mt)
#pragma unroll
        for (int nt = 0; nt < 4; ++nt)
          acc[mt][nt] = __builtin_amdgcn_mfma_f32_16x16x32_f16(wh[nt], zf[mt], acc[mt][nt], 0, 0, 0);
    }
    __syncthreads();  // all z reads of this layer done

    // epilogue: lane owns rows mt*16+n16, cols colb..colb+3 (one b64 write each)
#pragma unroll
    for (int nt = 0; nt < 4; ++nt) {
      int colb = wv * 64 + nt * 16 + quad * 4;
      float4 bi = make_float4(0.f, 0.f, 0.f, 0.f);
      float4 bn4 = bi;
      if (layer == 0) bi = *(const float4*)(b_in + colb);
      if (layer < 4) bn4 = *(const float4*)(bnv[layer] + colb);
#pragma unroll
      for (int mt = 0; mt < MT; ++mt) {
        int row = mt * 16 + n16;
        float v0 = acc[mt][nt][0] + bi.x;
        float v1 = acc[mt][nt][1] + bi.y;
        float v2 = acc[mt][nt][2] + bi.z;
        float v3 = acc[mt][nt][3] + bi.w;
        if (layer < 4) {
          v0 = v0 + tanh_fast(v0) + bn4.x;
          v1 = v1 + tanh_fast(v1) + bn4.y;
          v2 = v2 + tanh_fast(v2) + bn4.z;
          v3 = v3 + tanh_fast(v3) + bn4.w;
        }
        int idx = row * 256 + (((colb >> 3) ^ (row & 31)) * 8) + (colb & 7);
        uint2 zp;
        zp.x = rtz_pair16(v0, v1);
        zp.y = rtz_pair16(v2, v3);
        *(uint2*)&zpl[idx] = zp;
      }
    }
    __syncthreads();
  }

  // ---- logits: wave w reduces k-slice [w*64, w*64+64) ----
  f32x4 lacc[MT];
#pragma unroll
  for (int mt = 0; mt < MT; ++mt) lacc[mt] = (f32x4){0.f, 0.f, 0.f, 0.f};
  const unsigned* pw = pk + 5 * 32768 + ln * 4;
#pragma unroll
  for (int kk = 0; kk < 2; ++kk) {
    int kc = wv * 2 + kk;
    short8 wh = *(const short8*)(pw + kc * 256);
#pragma unroll
    for (int mt = 0; mt < MT; ++mt) {
      int mm = mt * 16 + n16;
      int idx = mm * 256 + (((kc * 4 + quad) ^ (mm & 31)) * 8);
      short8 zf = *(const short8*)&zpl[idx];
      lacc[mt] = __builtin_amdgcn_mfma_f32_16x16x32_f16(wh, zf, lacc[mt], 0, 0, 0);
    }
  }
  __syncthreads();  // done reading z plane
  float* pbuf = (float*)zpl;  // [wave][NR][16] floats = 16 KB for MT=4
#pragma unroll
  for (int mt = 0; mt < MT; ++mt) {
    int addr = wv * (NR * 16) + (mt * 16 + n16) * 16 + quad * 4;
    *(f32x4*)&pbuf[addr] = lacc[mt];
  }
  __syncthreads();
  if (t < NR) {
    int r = t;
    float lg[10];
    float mx = -1e30f;
#pragma unroll
    for (int j = 0; j < 10; ++j) {
      float s = b_out[j];
#pragma unroll
      for (int w2 = 0; w2 < 4; ++w2) s += pbuf[w2 * (NR * 16) + r * 16 + j];
      lg[j] = s;
      mx = fmaxf(mx, s);
    }
    float sum = 0.f;
#pragma unroll
    for (int j = 0; j < 10; ++j) {
      lg[j] = __expf(lg[j] - mx);
      sum += lg[j];
    }
    float inv = 1.0f / sum;
    float* op = out + (grow0 + r) * 10;
#pragma unroll
    for (int j = 0; j < 10; ++j) op[j] = lg[j] * inv;
  }
}

extern "C" void kernel_launch(void* const* d_in, const int* in_sizes, int n_in,
                              void* d_out, int out_size, void* d_ws, size_t ws_size,
                              hipStream_t stream) {
  const float* x     = (const float*)d_in[0];
  const float* w_in  = (const float*)d_in[1];
  const float* b_in  = (const float*)d_in[2];
  const float* w_out = (const float*)d_in[3];
  const float* b_out = (const float*)d_in[4];
  const float* w1 = (const float*)d_in[5];
  const float* b1 = (const float*)d_in[6];
  const float* w2 = (const float*)d_in[7];
  const float* b2 = (const float*)d_in[8];
  const float* w3 = (const float*)d_in[9];
  const float* b3 = (const float*)d_in[10];
  const float* w4 = (const float*)d_in[11];
  const float* b4 = (const float*)d_in[12];
  float* out = (float*)d_out;

  unsigned* pk = (unsigned*)d_ws;  // 165888 dwords

  ns_poly_k<<<384, 256, 0, stream>>>(w1, w2, w3, w4, w_in, w_out, pk);
  fused_k<4><<<1024, 256, 0, stream>>>(x, pk, b_in, b1, b2, b3, b4, b_out, out);
}